// Round 8
// baseline (53.589 us; speedup 1.0000x reference)
//
#include <hip/hip_runtime.h>
#include <math.h>

#define HW 16384
#define NPROJ 100
#define NB 8
#define NCH 32
#define CHLEN 512
#define EPSV 1e-6f

__device__ inline float4 add4(float4 a, float4 b) {
    return make_float4(a.x + b.x, a.y + b.y, a.z + b.z, a.w + b.w);
}
__device__ inline float4 sub4(float4 a, float4 b) {
    return make_float4(a.x - b.x, a.y - b.y, a.z - b.z, a.w - b.w);
}
__device__ inline float4 shfl_up4(float4 v, int off) {
    return make_float4(__shfl_up(v.x, off), __shfl_up(v.y, off),
                       __shfl_up(v.z, off), __shfl_up(v.w, off));
}

// Stage 1: per-(batch, chunk) partials: Xs = x0+x1+x2 (stored), sum(Xs), sum(y0),
// chunk max/argmax of x0 (first-occurrence). Block 0 zeroes the output.
__global__ __launch_bounds__(256) void partial_kernel(const float* __restrict__ X,
                                                      const float* __restrict__ Y,
                                                      float* __restrict__ Xs,
                                                      float* __restrict__ Pmax,
                                                      int* __restrict__ Pidx,
                                                      float* __restrict__ Psx,
                                                      float* __restrict__ Psy,
                                                      float* __restrict__ out) {
    const int blk = blockIdx.x;
    const int b = blk >> 5, c = blk & 31;
    const int tid = threadIdx.x, lane = tid & 63, wid = tid >> 6;
    if (blk == 0 && tid == 0) out[0] = 0.0f;  // consumed only by wproj (later kernel)
    const float* xb = X + (size_t)b * 3 * HW;
    const float* yb = Y + (size_t)b * 3 * HW;
    const int base = c * CHLEN;

    float mv = -INFINITY;
    int mi = 0;
    float sx = 0.0f, sy = 0.0f;
#pragma unroll
    for (int k = 0; k < 2; ++k) {
        int p = base + k * 256 + tid;
        float x0 = xb[p], x1 = xb[HW + p], x2 = xb[2 * HW + p], y0 = yb[p];
        float s = x0 + x1 + x2;
        Xs[(size_t)b * HW + p] = s;
        sx += s;
        sy += y0;
        if (x0 > mv) { mv = x0; mi = p; }   // strict > keeps earliest p
    }
#pragma unroll
    for (int off = 32; off > 0; off >>= 1) {
        float ov = __shfl_down(mv, off);
        int oi = __shfl_down(mi, off);
        sx += __shfl_down(sx, off);
        sy += __shfl_down(sy, off);
        if (ov > mv || (ov == mv && oi < mi)) { mv = ov; mi = oi; }
    }
    __shared__ float lmv[4], lsx[4], lsy[4];
    __shared__ int lmi[4];
    if (lane == 0) { lmv[wid] = mv; lmi[wid] = mi; lsx[wid] = sx; lsy[wid] = sy; }
    __syncthreads();
    if (tid == 0) {
        for (int w = 1; w < 4; ++w) {
            if (lmv[w] > lmv[0] || (lmv[w] == lmv[0] && lmi[w] < lmi[0])) {
                lmv[0] = lmv[w];
                lmi[0] = lmi[w];
            }
            lsx[0] += lsx[w];
            lsy[0] += lsy[w];
        }
        Pmax[blk] = lmv[0];
        Pidx[blk] = lmi[0];
        Psx[blk] = lsx[0];
        Psy[blk] = lsy[0];
    }
}

// Stage 2 (combine folded in): every block redundantly reduces the 8x32 partials,
// then builds Z[p][b] = (Xs+fix)*invX - Y0*invY, pixel-major float8 (32B/pixel).
__global__ __launch_bounds__(256) void zprep_kernel(const float* __restrict__ Pmax,
                                                    const int* __restrict__ Pidx,
                                                    const float* __restrict__ Psx,
                                                    const float* __restrict__ Psy,
                                                    const float* __restrict__ Xs,
                                                    const float* __restrict__ Y,
                                                    float* __restrict__ Z) {
    __shared__ float sInvX[8], sInvY[8], sFa[8];
    __shared__ int sFi[8];
    const int tid = threadIdx.x;
    const int c = tid & 31;
    {
        const int b = tid >> 5;
        float mv = Pmax[tid];
        int mi = Pidx[tid];
        float sx = Psx[tid];
        float sy = Psy[tid];
#pragma unroll
        for (int off = 16; off > 0; off >>= 1) {
            float ov = __shfl_down(mv, off, 32);
            int oi = __shfl_down(mi, off, 32);
            float osx = __shfl_down(sx, off, 32);
            float osy = __shfl_down(sy, off, 32);
            if (ov > mv || (ov == mv && oi < mi)) { mv = ov; mi = oi; }
            sx += osx;
            sy += osy;
        }
        if (c == 0) {
            float fa = (mv < EPSV) ? (EPSV - mv) : 0.0f;
            sFa[b] = fa;
            sFi[b] = mi;
            sInvX[b] = 1.0f / (sx + fa);
            sInvY[b] = 1.0f / sy;
        }
    }
    __syncthreads();
    const int p = blockIdx.x * 256 + tid;
    float z[8];
#pragma unroll
    for (int b = 0; b < 8; ++b) {
        float s = Xs[(size_t)b * HW + p];
        if (p == sFi[b]) s += sFa[b];
        z[b] = s * sInvX[b] - Y[(size_t)b * 3 * HW + p] * sInvY[b];
    }
    float4* zp = (float4*)(Z + (size_t)p * 8);
    zp[0] = make_float4(z[0], z[1], z[2], z[3]);
    zp[1] = make_float4(z[4], z[5], z[6], z[7]);
}

// Two blocks per projection (half h owns sorted positions [h*8192,(h+1)*8192)).
// Phase 1: full analytic ranksort (duplicated per half, cheap), scatter-keep own
// half into transposed 16KB LDS table; capture boundary id at pos 8192.
// Phase 2: each thread owns 8 positions x 8 channels, single float8 gather per
// pixel (each 64B line touched once), register prefix + wave/block scan.
// Cross-half scan carry uses sum(Z)=0: carry(half 1) = -ownSegmentTotal.
__global__ __launch_bounds__(1024, 4) void wproj_kernel(const float* __restrict__ proj,
                                                        const float* __restrict__ Z,
                                                        float* __restrict__ out) {
    __shared__ unsigned short sidT[8 * 1024];  // 16 KiB, transposed [m][tid]
    __shared__ int c_t[255];
    __shared__ unsigned char e_t[255];
    __shared__ float4 lwa[16], lwb[16];
    __shared__ float lred[16];
    __shared__ int sBound;  // pixel id at global sorted position 8192

    const int jp = blockIdx.x >> 1;
    const int h = blockIdx.x & 1;
    const int tid = threadIdx.x, lane = tid & 63, wid = tid >> 6;
    float a = proj[jp];
    float b = proj[NPROJ + jp];
    float inv = 1.0f / sqrtf(a * a + b * b);
    const float an = a * inv, bn = b * inv;
    const float ap = fabsf(an), bp = fabsf(bn);
    const bool flipi = (an < 0.0f), flipj = (bn < 0.0f);

    // ---- phase 1: ranksort; keep own half in transposed LDS table ----
    if (bp == 0.0f) {
        for (int t = tid; t < HW; t += 1024) {
            int i2 = t >> 7, j2 = t & 127;
            int ii = flipi ? 127 - i2 : i2;
            int jj = flipj ? 127 - j2 : j2;
            int idv = ii * 128 + jj;
            if (t == 8192) sBound = idv;
            int q = t - (h << 13);
            if ((unsigned)q < 8192u)
                sidT[(q & 7) * 1024 + (q >> 3)] = (unsigned short)idv;
        }
    } else {
        if (tid < 255) {
            int d = tid - 127;
            double v = (double)d * ((double)ap / (double)bp);
            double cv = ceil(v);
            e_t[tid] = (cv == v) ? 1 : 0;
            c_t[tid] = (int)fmin(fmax(cv, -128.0), 129.0);
        }
        __syncthreads();
        {
            const int j2 = tid & 127;
            const int g = tid >> 7;          // 0..7, each covers 16 rows of i2
            const int i2s = g * 16;
            const int jj = flipj ? 127 - j2 : j2;

            int wsum = 0;
#pragma unroll 8
            for (int q = 0; q < 128; ++q)
                wsum += min(max(c_t[i2s + q] + j2, 0), 128);
            int tsum = 0;
            for (int i2p = 1; i2p <= i2s; ++i2p) {
                if (e_t[i2p + 127]) {
                    int tj = j2 + c_t[i2p + 127];
                    if (tj >= 0 && tj < 128) tsum++;
                }
            }
            for (int q = 0; q < 16; ++q) {
                int i2 = i2s + q;
                if (q > 0) {
                    int dd_new = i2 + 127;
                    int dd_old = i2 - 1;
                    int cn = c_t[dd_new];
                    wsum += min(max(cn + j2, 0), 128);
                    wsum -= min(max(c_t[dd_old] + j2, 0), 128);
                    if (e_t[dd_new]) {
                        int tj = j2 + cn;
                        if (tj >= 0 && tj < 128) tsum++;
                    }
                }
                int pos = wsum + tsum;
                int ii = flipi ? 127 - i2 : i2;
                int idv = ii * 128 + jj;
                if (pos == 8192) sBound = idv;
                int ql = pos - (h << 13);
                if ((unsigned)ql < 8192u)
                    sidT[(ql & 7) * 1024 + (ql >> 3)] = (unsigned short)idv;
            }
        }
    }
    __syncthreads();

    // ---- phase 2: thread owns local positions [8*tid, 8*tid+7] ----
    int ids[9];
#pragma unroll
    for (int m = 0; m < 8; ++m) ids[m] = (int)sidT[m * 1024 + tid];
    ids[8] = (tid < 1023) ? (int)sidT[tid + 1]
                          : ((h == 0) ? sBound : ids[7]);  // h==1 tail unused

    float4 zva[8], zvb[8];
#pragma unroll
    for (int m = 0; m < 8; ++m) {
        const float4* zp = (const float4*)(Z + (size_t)ids[m] * 8);
        zva[m] = zp[0];
        zvb[m] = zp[1];
    }
#pragma unroll
    for (int m = 1; m < 8; ++m) {
        zva[m] = add4(zva[m], zva[m - 1]);
        zvb[m] = add4(zvb[m], zvb[m - 1]);
    }
    const float4 tota = zva[7], totb = zvb[7];

    float4 ia = tota, ib = totb;
#pragma unroll
    for (int off = 1; off < 64; off <<= 1) {
        float4 ua = shfl_up4(ia, off);
        float4 ub = shfl_up4(ib, off);
        if (lane >= off) { ia = add4(ia, ua); ib = add4(ib, ub); }
    }
    if (lane == 63) { lwa[wid] = ia; lwb[wid] = ib; }
    __syncthreads();

    float4 preA = sub4(ia, tota), preB = sub4(ib, totb);  // excl within wave
    float4 Ta = make_float4(0, 0, 0, 0), Tb = Ta;
#pragma unroll
    for (int w = 0; w < 16; ++w) {
        if (w < wid) { preA = add4(preA, lwa[w]); preB = add4(preB, lwb[w]); }
        Ta = add4(Ta, lwa[w]);
        Tb = add4(Tb, lwb[w]);
    }
    if (h == 1) {  // carry into half 1 = total(half 0) = -total(half 1)
        preA = sub4(preA, Ta);
        preB = sub4(preB, Tb);
    }

    float acc = 0.0f;
    float pc_cur = (float)(ids[0] >> 7) * an + (float)(ids[0] & 127) * bn;
#pragma unroll
    for (int m = 0; m < 8; ++m) {
        int idn = ids[m + 1];
        float pc_nxt = (float)(idn >> 7) * an + (float)(idn & 127) * bn;
        float4 cxa = add4(preA, zva[m]);
        float4 cxb = add4(preB, zvb[m]);
        float s8 = fabsf(cxa.x) + fabsf(cxa.y) + fabsf(cxa.z) + fabsf(cxa.w)
                 + fabsf(cxb.x) + fabsf(cxb.y) + fabsf(cxb.z) + fabsf(cxb.w);
        int gk = (h << 13) + tid * 8 + m;
        if (gk < HW - 1) acc += s8 * (pc_nxt - pc_cur);
        pc_cur = pc_nxt;
    }

    // block reduce
#pragma unroll
    for (int off = 32; off > 0; off >>= 1) acc += __shfl_down(acc, off);
    if (lane == 0) lred[wid] = acc;
    __syncthreads();
    if (tid == 0) {
        float r = 0.0f;
        for (int w = 0; w < 16; ++w) r += lred[w];
        atomicAdd(out, r * (1.0f / NPROJ));
    }
}

extern "C" void kernel_launch(void* const* d_in, const int* in_sizes, int n_in,
                              void* d_out, int out_size, void* d_ws, size_t ws_size,
                              hipStream_t stream) {
    const float* X = (const float*)d_in[0];
    const float* Y = (const float*)d_in[1];
    const float* proj = (const float*)d_in[2];
    float* out = (float*)d_out;

    char* ws = (char*)d_ws;
    size_t off = 0;
    float* Xs = (float*)(ws + off);     off += (size_t)NB * HW * sizeof(float);
    float* Z = (float*)(ws + off);      off += (size_t)NB * HW * sizeof(float);
    float* Pmax = (float*)(ws + off);   off += NB * NCH * sizeof(float);
    int* Pidx = (int*)(ws + off);       off += NB * NCH * sizeof(int);
    float* Psx = (float*)(ws + off);    off += NB * NCH * sizeof(float);
    float* Psy = (float*)(ws + off);    off += NB * NCH * sizeof(float);

    partial_kernel<<<NB * NCH, 256, 0, stream>>>(X, Y, Xs, Pmax, Pidx, Psx, Psy, out);
    zprep_kernel<<<HW / 256, 256, 0, stream>>>(Pmax, Pidx, Psx, Psy, Xs, Y, Z);
    wproj_kernel<<<NPROJ * 2, 1024, 0, stream>>>(proj, Z, out);
}

// Round 9
// 40.058 us; speedup vs baseline: 1.3378x; 1.3378x over previous
//
#include <hip/hip_runtime.h>
#include <math.h>

#define HW 16384
#define NPROJ 100
#define NB 8
#define NCH 32
#define CHLEN 512
#define EPSV 1e-6f

__device__ inline float4 add4(float4 a, float4 b) {
    return make_float4(a.x + b.x, a.y + b.y, a.z + b.z, a.w + b.w);
}
__device__ inline float4 sub4(float4 a, float4 b) {
    return make_float4(a.x - b.x, a.y - b.y, a.z - b.z, a.w - b.w);
}
__device__ inline float4 shfl_up4(float4 v, int off) {
    return make_float4(__shfl_up(v.x, off), __shfl_up(v.y, off),
                       __shfl_up(v.z, off), __shfl_up(v.w, off));
}

// Stage 1: per-(batch, chunk) partials: Xs = x0+x1+x2 (stored), sum(Xs), sum(y0),
// chunk max/argmax of x0 (first-occurrence). Block 0 zeroes the output.
__global__ __launch_bounds__(256) void partial_kernel(const float* __restrict__ X,
                                                      const float* __restrict__ Y,
                                                      float* __restrict__ Xs,
                                                      float* __restrict__ Pmax,
                                                      int* __restrict__ Pidx,
                                                      float* __restrict__ Psx,
                                                      float* __restrict__ Psy,
                                                      float* __restrict__ out) {
    const int blk = blockIdx.x;
    const int b = blk >> 5, c = blk & 31;
    const int tid = threadIdx.x, lane = tid & 63, wid = tid >> 6;
    if (blk == 0 && tid == 0) out[0] = 0.0f;  // consumed only by wproj (later kernel)
    const float* xb = X + (size_t)b * 3 * HW;
    const float* yb = Y + (size_t)b * 3 * HW;
    const int base = c * CHLEN;

    float mv = -INFINITY;
    int mi = 0;
    float sx = 0.0f, sy = 0.0f;
#pragma unroll
    for (int k = 0; k < 2; ++k) {
        int p = base + k * 256 + tid;
        float x0 = xb[p], x1 = xb[HW + p], x2 = xb[2 * HW + p], y0 = yb[p];
        float s = x0 + x1 + x2;
        Xs[(size_t)b * HW + p] = s;
        sx += s;
        sy += y0;
        if (x0 > mv) { mv = x0; mi = p; }   // strict > keeps earliest p
    }
#pragma unroll
    for (int off = 32; off > 0; off >>= 1) {
        float ov = __shfl_down(mv, off);
        int oi = __shfl_down(mi, off);
        sx += __shfl_down(sx, off);
        sy += __shfl_down(sy, off);
        if (ov > mv || (ov == mv && oi < mi)) { mv = ov; mi = oi; }
    }
    __shared__ float lmv[4], lsx[4], lsy[4];
    __shared__ int lmi[4];
    if (lane == 0) { lmv[wid] = mv; lmi[wid] = mi; lsx[wid] = sx; lsy[wid] = sy; }
    __syncthreads();
    if (tid == 0) {
        for (int w = 1; w < 4; ++w) {
            if (lmv[w] > lmv[0] || (lmv[w] == lmv[0] && lmi[w] < lmi[0])) {
                lmv[0] = lmv[w];
                lmi[0] = lmi[w];
            }
            lsx[0] += lsx[w];
            lsy[0] += lsy[w];
        }
        Pmax[blk] = lmv[0];
        Pidx[blk] = lmi[0];
        Psx[blk] = lsx[0];
        Psy[blk] = lsy[0];
    }
}

// Stage 2 (combine folded in): every block redundantly reduces the 8x32 partials,
// then builds Z[p][b] = (Xs+fix)*invX - Y0*invY, pixel-major float8 (32B/pixel).
__global__ __launch_bounds__(256) void zprep_kernel(const float* __restrict__ Pmax,
                                                    const int* __restrict__ Pidx,
                                                    const float* __restrict__ Psx,
                                                    const float* __restrict__ Psy,
                                                    const float* __restrict__ Xs,
                                                    const float* __restrict__ Y,
                                                    float* __restrict__ Z) {
    __shared__ float sInvX[8], sInvY[8], sFa[8];
    __shared__ int sFi[8];
    const int tid = threadIdx.x;
    const int c = tid & 31;
    {
        const int b = tid >> 5;
        float mv = Pmax[tid];
        int mi = Pidx[tid];
        float sx = Psx[tid];
        float sy = Psy[tid];
#pragma unroll
        for (int off = 16; off > 0; off >>= 1) {
            float ov = __shfl_down(mv, off, 32);
            int oi = __shfl_down(mi, off, 32);
            float osx = __shfl_down(sx, off, 32);
            float osy = __shfl_down(sy, off, 32);
            if (ov > mv || (ov == mv && oi < mi)) { mv = ov; mi = oi; }
            sx += osx;
            sy += osy;
        }
        if (c == 0) {
            float fa = (mv < EPSV) ? (EPSV - mv) : 0.0f;
            sFa[b] = fa;
            sFi[b] = mi;
            sInvX[b] = 1.0f / (sx + fa);
            sInvY[b] = 1.0f / sy;
        }
    }
    __syncthreads();
    const int p = blockIdx.x * 256 + tid;
    float z[8];
#pragma unroll
    for (int b = 0; b < 8; ++b) {
        float s = Xs[(size_t)b * HW + p];
        if (p == sFi[b]) s += sFa[b];
        z[b] = s * sInvX[b] - Y[(size_t)b * 3 * HW + p] * sInvY[b];
    }
    float4* zp = (float4*)(Z + (size_t)p * 8);
    zp[0] = make_float4(z[0], z[1], z[2], z[3]);
    zp[1] = make_float4(z[4], z[5], z[6], z[7]);
}

// Two blocks per projection (half h owns sorted positions [h*8192,(h+1)*8192)).
// Phase 1: full analytic ranksort (duplicated per half, cheap), keep own half in
// a transposed 16KB LDS table; capture boundary id at pos 8192.
// Phase 2: 2 sequential channel-group passes; per pass each thread gathers 8
// float4 (32 VGPR live -- no spill), register prefix + wave/block scan.
// Cross-half scan carry uses sum(Z)=0: carry(half 1) = -ownSegmentTotal.
// amdgpu_waves_per_eu(4,4): 4 waves/EU => 128-VGPR budget (16-wave block = 1
// block/CU, which a 200-block grid saturates anyway).
__global__ __launch_bounds__(1024)
__attribute__((amdgpu_waves_per_eu(4, 4)))
void wproj_kernel(const float* __restrict__ proj,
                  const float* __restrict__ Z,
                  float* __restrict__ out) {
    __shared__ unsigned short sidT[8 * 1024];  // 16 KiB, transposed [m][tid]
    __shared__ int c_t[255];
    __shared__ unsigned char e_t[255];
    __shared__ float4 lw[16];
    __shared__ float lred[16];
    __shared__ int sBound;  // pixel id at global sorted position 8192

    const int jp = blockIdx.x >> 1;
    const int h = blockIdx.x & 1;
    const int tid = threadIdx.x, lane = tid & 63, wid = tid >> 6;
    float a = proj[jp];
    float b = proj[NPROJ + jp];
    float inv = 1.0f / sqrtf(a * a + b * b);
    const float an = a * inv, bn = b * inv;
    const float ap = fabsf(an), bp = fabsf(bn);
    const bool flipi = (an < 0.0f), flipj = (bn < 0.0f);

    // ---- phase 1: ranksort; keep own half in transposed LDS table ----
    if (bp == 0.0f) {
        for (int t = tid; t < HW; t += 1024) {
            int i2 = t >> 7, j2 = t & 127;
            int ii = flipi ? 127 - i2 : i2;
            int jj = flipj ? 127 - j2 : j2;
            int idv = ii * 128 + jj;
            if (t == 8192) sBound = idv;
            int q = t - (h << 13);
            if ((unsigned)q < 8192u)
                sidT[(q & 7) * 1024 + (q >> 3)] = (unsigned short)idv;
        }
    } else {
        if (tid < 255) {
            int d = tid - 127;
            double v = (double)d * ((double)ap / (double)bp);
            double cv = ceil(v);
            e_t[tid] = (cv == v) ? 1 : 0;
            c_t[tid] = (int)fmin(fmax(cv, -128.0), 129.0);
        }
        __syncthreads();
        {
            const int j2 = tid & 127;
            const int g = tid >> 7;          // 0..7, each covers 16 rows of i2
            const int i2s = g * 16;
            const int jj = flipj ? 127 - j2 : j2;

            int wsum = 0;
#pragma unroll 8
            for (int q = 0; q < 128; ++q)
                wsum += min(max(c_t[i2s + q] + j2, 0), 128);
            int tsum = 0;
            for (int i2p = 1; i2p <= i2s; ++i2p) {
                if (e_t[i2p + 127]) {
                    int tj = j2 + c_t[i2p + 127];
                    if (tj >= 0 && tj < 128) tsum++;
                }
            }
            for (int q = 0; q < 16; ++q) {
                int i2 = i2s + q;
                if (q > 0) {
                    int dd_new = i2 + 127;
                    int dd_old = i2 - 1;
                    int cn = c_t[dd_new];
                    wsum += min(max(cn + j2, 0), 128);
                    wsum -= min(max(c_t[dd_old] + j2, 0), 128);
                    if (e_t[dd_new]) {
                        int tj = j2 + cn;
                        if (tj >= 0 && tj < 128) tsum++;
                    }
                }
                int pos = wsum + tsum;
                int ii = flipi ? 127 - i2 : i2;
                int idv = ii * 128 + jj;
                if (pos == 8192) sBound = idv;
                int ql = pos - (h << 13);
                if ((unsigned)ql < 8192u)
                    sidT[(ql & 7) * 1024 + (ql >> 3)] = (unsigned short)idv;
            }
        }
    }
    __syncthreads();

    // ---- phase 2: thread owns local positions [8*tid, 8*tid+7] ----
    int ids[9];
#pragma unroll
    for (int m = 0; m < 8; ++m) ids[m] = (int)sidT[m * 1024 + tid];
    ids[8] = (tid < 1023) ? (int)sidT[tid + 1]
                          : ((h == 0) ? sBound : ids[7]);  // h==1 tail unused

    float acc = 0.0f;
#pragma unroll 1
    for (int cg = 0; cg < 2; ++cg) {
        float4 zv[8];
#pragma unroll
        for (int m = 0; m < 8; ++m)
            zv[m] = *(const float4*)(Z + (size_t)ids[m] * 8 + cg * 4);
#pragma unroll
        for (int m = 1; m < 8; ++m) zv[m] = add4(zv[m], zv[m - 1]);
        const float4 tot = zv[7];

        float4 ia = tot;
#pragma unroll
        for (int off = 1; off < 64; off <<= 1) {
            float4 ua = shfl_up4(ia, off);
            if (lane >= off) ia = add4(ia, ua);
        }
        if (lane == 63) lw[wid] = ia;
        __syncthreads();

        float4 pre = sub4(ia, tot);  // exclusive within wave
        float4 T = make_float4(0, 0, 0, 0);
#pragma unroll
        for (int w = 0; w < 16; ++w) {
            if (w < wid) pre = add4(pre, lw[w]);
            T = add4(T, lw[w]);
        }
        if (h == 1) pre = sub4(pre, T);  // carry = total(half0) = -total(half1)

        float pc_cur = (float)(ids[0] >> 7) * an + (float)(ids[0] & 127) * bn;
#pragma unroll
        for (int m = 0; m < 8; ++m) {
            int idn = ids[m + 1];
            float pc_nxt = (float)(idn >> 7) * an + (float)(idn & 127) * bn;
            float4 cx = add4(pre, zv[m]);
            float s4 = fabsf(cx.x) + fabsf(cx.y) + fabsf(cx.z) + fabsf(cx.w);
            int gk = (h << 13) + tid * 8 + m;
            if (gk < HW - 1) acc += s4 * (pc_nxt - pc_cur);
            pc_cur = pc_nxt;
        }
        __syncthreads();  // protect lw reuse in next pass
    }

    // block reduce
#pragma unroll
    for (int off = 32; off > 0; off >>= 1) acc += __shfl_down(acc, off);
    if (lane == 0) lred[wid] = acc;
    __syncthreads();
    if (tid == 0) {
        float r = 0.0f;
        for (int w = 0; w < 16; ++w) r += lred[w];
        atomicAdd(out, r * (1.0f / NPROJ));
    }
}

extern "C" void kernel_launch(void* const* d_in, const int* in_sizes, int n_in,
                              void* d_out, int out_size, void* d_ws, size_t ws_size,
                              hipStream_t stream) {
    const float* X = (const float*)d_in[0];
    const float* Y = (const float*)d_in[1];
    const float* proj = (const float*)d_in[2];
    float* out = (float*)d_out;

    char* ws = (char*)d_ws;
    size_t off = 0;
    float* Xs = (float*)(ws + off);     off += (size_t)NB * HW * sizeof(float);
    float* Z = (float*)(ws + off);      off += (size_t)NB * HW * sizeof(float);
    float* Pmax = (float*)(ws + off);   off += NB * NCH * sizeof(float);
    int* Pidx = (int*)(ws + off);       off += NB * NCH * sizeof(int);
    float* Psx = (float*)(ws + off);    off += NB * NCH * sizeof(float);
    float* Psy = (float*)(ws + off);    off += NB * NCH * sizeof(float);

    partial_kernel<<<NB * NCH, 256, 0, stream>>>(X, Y, Xs, Pmax, Pidx, Psx, Psy, out);
    zprep_kernel<<<HW / 256, 256, 0, stream>>>(Pmax, Pidx, Psx, Psy, Xs, Y, Z);
    wproj_kernel<<<NPROJ * 2, 1024, 0, stream>>>(proj, Z, out);
}